// Round 6
// baseline (134.377 us; speedup 1.0000x reference)
//
#include <hip/hip_runtime.h>

// B=64, IMG=1024, IND=64, E=4, FF=16. Inputs fp32, output fp32.
// Validated algebra (absmax 0.0 through round 5): scalar token iv through
// affine stem -> softmax weight exp(a_r * x_t) with a_r = 0.5*(c1*iv_r + c0);
// attention out = HB*rho + HC, rho = S1/S0. exp Taylor K=12; S0,S1 are
// 13-term polynomials in a with per-batch f64 moments M_k = sum_t x^k
// (summation order bit-identical to the two-kernel winner).
//
// Round 15 (on top of round-14's 131.5us one-dispatch handoff):
//  - all LDS weight reads vectorized to ds_read_b128 (f4, 16B-aligned
//    offsets); per-accumulator FP add order preserved exactly.
//  - weight staging vectorized (float4 copies).
//  - ind-block poll moved to idle wave 1, overlapping wave 0's row tails.
// Handoff: img block (b,q) publishes 3 partials as self-validating u64
// (bits(v) | ~bits(v)<<32) relaxed agent atomics; ws poison (repeated 32-bit
// pattern) has hi==lo so hi==~lo certifies a producer write -- no memset.
// Ind block b finalizes its batch; bounded spin + bit-identical recompute
// fallback keeps it hang-proof.
#define B_    64
#define IMG_  1024
#define IND_  64
#define NTHR  256
#define NBLK_IMG (B_ * 4)          // 4 img blocks/batch, 256 rows each
#define NBLK  (NBLK_IMG + B_)      // 320
#define SPIN_MAX 65536

enum {
  W_IN = 0, B_IN = 4, QKV_W = 8, QKV_B = 56, O_W = 68, O_B = 84,
  LN1G = 88, LN1B = 92, FF1W = 96, FF1B = 160, FF2W = 176, FF2B = 240,
  LN2G = 244, LN2B = 248, W_OUT = 252, B_OUT = 256, WTOT = 257
};

struct KArgs {
  const float* in[36];
  unsigned long long* pout;  // [B_][4][3] packed self-validating partials (d_ws)
  float* out;                // [B_][3] (d_out)
};

struct __align__(16) f4 { float v[4]; };

__device__ __forceinline__ f4 ld4(const float* p) {
  return *reinterpret_cast<const f4*>(p);
}

__device__ __forceinline__ void stage4(float* dst, const float* src, int n4, int tid) {
  for (int i = tid; i < n4; i += NTHR)
    reinterpret_cast<f4*>(dst)[i] = reinterpret_cast<const f4*>(src)[i];
}

__device__ __forceinline__ void stage1(float* dst, const float* src, int n, int tid) {
  for (int i = tid; i < n; i += NTHR) dst[i] = src[i];
}

__device__ __forceinline__ double wave_sum_d(double v) {
  v += __shfl_xor(v, 1);  v += __shfl_xor(v, 2);  v += __shfl_xor(v, 4);
  v += __shfl_xor(v, 8);  v += __shfl_xor(v, 16); v += __shfl_xor(v, 32);
  return v;
}

// Per-row tail. All weight reads are b128; every scalar accumulator sums its
// terms in the same index order as the validated scalar version.
__device__ __forceinline__ float row_tail(const float* __restrict__ w,
                                          float ivr, const float* __restrict__ Mf) {
  const f4 win = ld4(w + W_IN), bin = ld4(w + B_IN);

  float a0[4] = {0,0,0,0}, b0[4] = {0,0,0,0}, a1[4] = {0,0,0,0};
  float a2[4] = {0,0,0,0}, b2[4] = {0,0,0,0};
#pragma unroll
  for (int e = 0; e < 4; e++) {                     // e-outer; per-j order over e preserved
    const float we = win.v[e], be = bin.v[e];
    const f4 qr = ld4(w + QKV_W + e * 12);
    const f4 kr = ld4(w + QKV_W + e * 12 + 4);
    const f4 vr = ld4(w + QKV_W + e * 12 + 8);
#pragma unroll
    for (int j = 0; j < 4; j++) {
      a0[j] += we * qr.v[j];  b0[j] += be * qr.v[j];
      a1[j] += we * kr.v[j];
      a2[j] += we * vr.v[j];  b2[j] += be * vr.v[j];
    }
  }
  const f4 qkb0 = ld4(w + QKV_B), qkb8 = ld4(w + QKV_B + 8);
  float c1 = 0.f, c0 = 0.f;
#pragma unroll
  for (int j = 0; j < 4; j++) {                     // j ascending, as before
    const float kdj = a1[j];
    c1 += a0[j] * kdj;
    c0 += (b0[j] + qkb0.v[j]) * kdj;
  }
  float s1[4] = {0,0,0,0}, s2[4] = {0,0,0,0};
#pragma unroll
  for (int f = 0; f < 4; f++) {                     // f-outer; per-j order over f preserved
    const f4 ow = ld4(w + O_W + f * 4);
    const float vdf = a2[f], vbf = b2[f] + qkb8.v[f];
#pragma unroll
    for (int j = 0; j < 4; j++) { s1[j] += vdf * ow.v[j]; s2[j] += vbf * ow.v[j]; }
  }
  const f4 ob = ld4(w + O_B);
  float HB[4], HC[4];
#pragma unroll
  for (int j = 0; j < 4; j++) { HB[j] = s1[j]; HC[j] = bin.v[j] + s2[j] + ob.v[j]; }

  const float a = 0.5f * (c1 * ivr + c0);           // natural-exp coefficient
  float t = 1.f, S0 = Mf[0], S1 = Mf[1];
#pragma unroll
  for (int k = 1; k <= 12; k++) {
    t *= a * (1.0f / (float)k);
    S0 = fmaf(t, Mf[k], S0);
    S1 = fmaf(t, Mf[k + 1], S1);
  }
  const float rho = S1 / S0;

  float h[4];
#pragma unroll
  for (int j = 0; j < 4; j++) h[j] = win.v[j] * ivr + HB[j] * rho + HC[j];
  {
    const f4 g = ld4(w + LN1G), bb = ld4(w + LN1B);
    const float mn = 0.25f * (h[0] + h[1] + h[2] + h[3]);
    float v = 0.f;
#pragma unroll
    for (int j = 0; j < 4; j++) { const float d = h[j] - mn; v += d * d; }
    const float rs = rsqrtf(v * 0.25f + 1e-5f);
#pragma unroll
    for (int j = 0; j < 4; j++) h[j] = (h[j] - mn) * rs * g.v[j] + bb.v[j];
  }

  float u[16];
#pragma unroll
  for (int t4 = 0; t4 < 4; t4++) {
    const f4 fb1 = ld4(w + FF1B + t4 * 4);
#pragma unroll
    for (int i = 0; i < 4; i++) u[t4 * 4 + i] = fb1.v[i];
  }
#pragma unroll
  for (int j = 0; j < 4; j++) {                     // j ascending per u[tt], as before
#pragma unroll
    for (int t4 = 0; t4 < 4; t4++) {
      const f4 w1 = ld4(w + FF1W + j * 16 + t4 * 4);
#pragma unroll
      for (int i = 0; i < 4; i++) u[t4 * 4 + i] += h[j] * w1.v[i];
    }
  }
  const f4 ffb2 = ld4(w + FF2B);
  float f2[4];
#pragma unroll
  for (int j = 0; j < 4; j++) f2[j] = ffb2.v[j];
#pragma unroll
  for (int tt = 0; tt < 16; tt++) {                 // tt ascending per f2[j], as before
    const float uu = fmaxf(u[tt], 0.f);
    const f4 w2 = ld4(w + FF2W + tt * 4);
#pragma unroll
    for (int j = 0; j < 4; j++) f2[j] += uu * w2.v[j];
  }
  float h2[4];
#pragma unroll
  for (int j = 0; j < 4; j++) h2[j] = h[j] + f2[j];
  {
    const f4 g = ld4(w + LN2G), bb = ld4(w + LN2B);
    const float mn = 0.25f * (h2[0] + h2[1] + h2[2] + h2[3]);
    float v = 0.f;
#pragma unroll
    for (int j = 0; j < 4; j++) { const float d = h2[j] - mn; v += d * d; }
    const float rs = rsqrtf(v * 0.25f + 1e-5f);
#pragma unroll
    for (int j = 0; j < 4; j++) h2[j] = (h2[j] - mn) * rs * g.v[j] + bb.v[j];
  }
  const f4 wo = ld4(w + W_OUT);
  float outv = w[B_OUT];
#pragma unroll
  for (int j = 0; j < 4; j++) outv += h2[j] * wo.v[j];
  return outv;
}

__device__ __forceinline__ unsigned long long pack_valid(float v) {
  const unsigned int lo = __float_as_uint(v);
  return (unsigned long long)lo | ((unsigned long long)(~lo) << 32);
}

__device__ __forceinline__ void stage_all(float* w, const KArgs& A, bool img_set, int tid) {
  stage4(w + W_IN,  A.in[img_set ? 2 : 4], 1,  tid);
  stage4(w + B_IN,  A.in[img_set ? 3 : 5], 1,  tid);
  stage4(w + W_OUT, A.in[img_set ? 6 : 8], 1,  tid);
  stage1(w + B_OUT, A.in[img_set ? 7 : 9], 1,  tid);
  const int tb = img_set ? 10 : 22;
  stage4(w + QKV_W, A.in[tb + 0], 12, tid);
  stage4(w + QKV_B, A.in[tb + 1], 3,  tid);
  stage4(w + O_W,   A.in[tb + 2], 4,  tid);
  stage4(w + O_B,   A.in[tb + 3], 1,  tid);
  stage4(w + LN1G,  A.in[tb + 4], 1,  tid);
  stage4(w + LN1B,  A.in[tb + 5], 1,  tid);
  stage4(w + FF1W,  A.in[tb + 6], 16, tid);
  stage4(w + FF1B,  A.in[tb + 7], 4,  tid);
  stage4(w + FF2W,  A.in[tb + 8], 16, tid);
  stage4(w + FF2B,  A.in[tb + 9], 1,  tid);
  stage4(w + LN2G,  A.in[tb + 10], 1, tid);
  stage4(w + LN2B,  A.in[tb + 11], 1, tid);
}

__global__ __launch_bounds__(NTHR) void fused(KArgs A) {
  const int blk = blockIdx.x;
  const int tid = threadIdx.x;
  const bool is_img = blk < NBLK_IMG;

  __shared__ __align__(16) float w[WTOT];
  __shared__ double mws[4][13];
  __shared__ float red[4][3];
  __shared__ float vals[12];
  __shared__ int okflag;

  int batch;
  const float* xin;
  if (is_img) { batch = blk >> 2;        xin = A.in[0] + batch * IMG_; }
  else        { batch = blk - NBLK_IMG;  xin = A.in[1] + batch * IND_; }

  // ---- stage weights (barrier deferred: moments touch no LDS weights) ----
  stage_all(w, A, is_img, tid);

  // ---- tokens straight to registers ----
  float tok[4];
  if (is_img) {
#pragma unroll
    for (int q = 0; q < 4; q++) tok[q] = xin[tid + 256 * q];
  } else {
    tok[0] = (tid < IND_) ? xin[tid] : 0.f;
    tok[1] = tok[2] = tok[3] = 0.f;
  }

  // ---- per-batch moments M_1..M_13 (f64, order identical to winner) ----
  double m[13];
#pragma unroll
  for (int k = 0; k < 13; k++) m[k] = 0.0;
  if (is_img) {
#pragma unroll
    for (int q = 0; q < 4; q++) {            // tokens tid, tid+256, tid+512, tid+768
      const double x = (double)tok[q];
      double px = x;
#pragma unroll
      for (int k = 0; k < 13; k++) { m[k] += px; px *= x; }
    }
  } else {
    const double x = (double)tok[0];         // 0 for tid>=64 -> contributes 0
    double px = x;
#pragma unroll
    for (int k = 0; k < 13; k++) { m[k] += px; px *= x; }
  }
#pragma unroll
  for (int k = 0; k < 13; k++) m[k] = wave_sum_d(m[k]);
  if ((tid & 63) == 0) {
    const int wv = tid >> 6;
#pragma unroll
    for (int k = 0; k < 13; k++) mws[wv][k] = m[k];
  }
  __syncthreads();             // covers weight staging AND mws publication
  float Mf[14];
  Mf[0] = (float)(is_img ? IMG_ : IND_);
#pragma unroll
  for (int k = 0; k < 13; k++)
    Mf[k + 1] = (float)(mws[0][k] + mws[1][k] + mws[2][k] + mws[3][k]);

  // ---- one row per thread: tail + classifier partials ----
  // In ind blocks, idle wave 1 polls the img slots concurrently with wave 0's
  // row tails, hiding the cross-XCD handoff latency.
  const bool active = is_img || (tid < IND_);
  const int q = blk & 3;
  float p0 = 0.f, p1 = 0.f, p2 = 0.f;
  if (active) {
    const float ivr = is_img ? tok[q] : tok[0];
    const float outv = row_tail(w, ivr, Mf);
    const int g = is_img ? (q * 256 + tid) : (IMG_ + tid);
    const float* wc = A.in[34] + 3 * g;
    p0 = outv * wc[0]; p1 = outv * wc[1]; p2 = outv * wc[2];
  } else if (!is_img && tid >= 64 && tid < 128) {
    bool got = false;
    if (tid < 76) {                          // 12 lanes, one slot each
      unsigned long long* slot = A.pout + (unsigned long long)(batch * 12 + (tid - 64));
      for (int it = 0; it < SPIN_MAX; ++it) {
        const unsigned long long v =
            __hip_atomic_load(slot, __ATOMIC_RELAXED, __HIP_MEMORY_SCOPE_AGENT);
        if ((unsigned int)(v >> 32) == ~(unsigned int)v) {   // poison has hi==lo
          vals[tid - 64] = __uint_as_float((unsigned int)v);
          got = true;
          break;
        }
        __builtin_amdgcn_s_sleep(1);
      }
    }
    const unsigned long long bal = __ballot(got);
    if (tid == 64) okflag = ((bal & 0xFFFull) == 0xFFFull);
  }
#pragma unroll
  for (int msk = 1; msk < 64; msk <<= 1) {
    p0 += __shfl_xor(p0, msk); p1 += __shfl_xor(p1, msk); p2 += __shfl_xor(p2, msk);
  }
  if ((tid & 63) == 0) {
    const int wv = tid >> 6;
    red[wv][0] = p0; red[wv][1] = p1; red[wv][2] = p2;
  }
  __syncthreads();             // red, vals, okflag all published

  if (is_img) {
    // ---- publish self-validating packed partials (relaxed agent atomics) ----
    if (tid == 0) {
      const float s0 = red[0][0] + red[1][0] + red[2][0] + red[3][0];
      const float s1 = red[0][1] + red[1][1] + red[2][1] + red[3][1];
      const float s2 = red[0][2] + red[1][2] + red[2][2] + red[3][2];
      unsigned long long* slot = A.pout + (unsigned long long)(batch * 12 + q * 3);
      __hip_atomic_store(&slot[0], pack_valid(s0), __ATOMIC_RELAXED, __HIP_MEMORY_SCOPE_AGENT);
      __hip_atomic_store(&slot[1], pack_valid(s1), __ATOMIC_RELAXED, __HIP_MEMORY_SCOPE_AGENT);
      __hip_atomic_store(&slot[2], pack_valid(s2), __ATOMIC_RELAXED, __HIP_MEMORY_SCOPE_AGENT);
    }
    return;
  }

  // ---- ind block = per-batch finalizer ----
  // own ind partial, saved BEFORE any fallback overwrites red
  const float si0 = red[0][0] + red[1][0] + red[2][0] + red[3][0];
  const float si1 = red[0][1] + red[1][1] + red[2][1] + red[3][1];
  const float si2 = red[0][2] + red[1][2] + red[2][2] + red[3][2];

  float sq[4][3];                 // fallback img partials (bit-identical path)
  const bool fb = !okflag;
  if (fb) {
    // re-stage t1 weights (everyone is done reading the t2 set)
    stage_all(w, A, true, tid);

    const float* xinI = A.in[0] + batch * IMG_;
    float tokI[4];
#pragma unroll
    for (int qq = 0; qq < 4; qq++) tokI[qq] = xinI[tid + 256 * qq];

    double mI[13];
#pragma unroll
    for (int k = 0; k < 13; k++) mI[k] = 0.0;
#pragma unroll
    for (int qq = 0; qq < 4; qq++) {
      const double x = (double)tokI[qq];
      double px = x;
#pragma unroll
      for (int k = 0; k < 13; k++) { mI[k] += px; px *= x; }
    }
#pragma unroll
    for (int k = 0; k < 13; k++) mI[k] = wave_sum_d(mI[k]);
    if ((tid & 63) == 0) {
      const int wv = tid >> 6;
#pragma unroll
      for (int k = 0; k < 13; k++) mws[wv][k] = mI[k];
    }
    __syncthreads();             // covers w restage AND mws
    float MfI[14];
    MfI[0] = (float)IMG_;
#pragma unroll
    for (int k = 0; k < 13; k++)
      MfI[k + 1] = (float)(mws[0][k] + mws[1][k] + mws[2][k] + mws[3][k]);

    for (int qq = 0; qq < 4; qq++) {
      const float outv = row_tail(w, tokI[qq], MfI);
      const float* wc = A.in[34] + 3 * (qq * 256 + tid);
      float a0 = outv * wc[0], a1 = outv * wc[1], a2 = outv * wc[2];
#pragma unroll
      for (int msk = 1; msk < 64; msk <<= 1) {
        a0 += __shfl_xor(a0, msk); a1 += __shfl_xor(a1, msk); a2 += __shfl_xor(a2, msk);
      }
      if ((tid & 63) == 0) {
        const int wv = tid >> 6;
        red[wv][0] = a0; red[wv][1] = a1; red[wv][2] = a2;
      }
      __syncthreads();
#pragma unroll
      for (int c = 0; c < 3; c++)
        sq[qq][c] = red[0][c] + red[1][c] + red[2][c] + red[3][c];
      __syncthreads();           // before next qq overwrites red
    }
  }

  if (tid == 0) {
    const float* bc = A.in[35];
    float z[3];
#pragma unroll
    for (int c = 0; c < 3; c++) {
      float s = bc[c];
      if (fb) {
#pragma unroll
        for (int i = 0; i < 4; i++) s += sq[i][c];            // winner order
      } else {
#pragma unroll
        for (int i = 0; i < 4; i++) s += vals[i * 3 + c];     // winner order
      }
      s += (c == 0) ? si0 : (c == 1) ? si1 : si2;             // own ind partial
      z[c] = s;
    }
    const float mx = fmaxf(z[0], fmaxf(z[1], z[2]));
    const float e0 = __expf(z[0] - mx), e1 = __expf(z[1] - mx), e2 = __expf(z[2] - mx);
    const float rs = 1.f / (e0 + e1 + e2);
    A.out[batch * 3 + 0] = e0 * rs;
    A.out[batch * 3 + 1] = e1 * rs;
    A.out[batch * 3 + 2] = e2 * rs;
  }
}

extern "C" void kernel_launch(void* const* d_in, const int* in_sizes, int n_in,
                              void* d_out, int out_size, void* d_ws, size_t ws_size,
                              hipStream_t stream) {
  KArgs A;
  for (int i = 0; i < 36; i++) A.in[i] = (const float*)d_in[i];
  A.pout = (unsigned long long*)d_ws;   // 768 u64 slots, self-validating
  A.out  = (float*)d_out;

  fused<<<NBLK, NTHR, 0, stream>>>(A);
}

// Round 7
// 131.356 us; speedup vs baseline: 1.0230x; 1.0230x over previous
//
#include <hip/hip_runtime.h>

// B=64, IMG=1024, IND=64, E=4, FF=16. Inputs fp32, output fp32.
// Validated algebra (prior session, absmax 0.0): scalar token iv through
// affine stem -> softmax weight exp(a_r * x_t) with a_r = 0.5*(c1*iv_r + c0)
// (row const cancels); attention out = HB*rho + HC, rho = S1/S0.
// exp(z) Taylor K=12 (|z| <~ 1, rel err ~4e-10); S0,S1 are 13-term
// polynomials in a with per-batch moments M_k = sum_t x^k (f64 accumulation,
// identical summation order to the 134.3us two-kernel winner).
//
// Round 16 = exact revert to round-14/round-5's 131.5us kernel (measured
// best). Round 15's f4-vectorized row_tail + wave-1 poll regressed to 134.4
// (register pressure / scheduling, cause not isolatable -- fused kernel is
// below the rocprof top-5 cutoff). Structure retained here:
//  - ONE dispatch, no memset/ticket/grid-sync.
//  - img block (b,q) publishes 3 classifier partials as self-validating u64
//    (bits(v) | ~bits(v)<<32) relaxed agent atomics; ws poison is a repeated
//    32-bit fill pattern so hi==lo, and hi==~lo certifies a producer write.
//  - ind block b (IDs 256..319) finalizes its batch: 12 lanes poll the 4x3
//    slots (bounded spin + s_sleep); on timeout, bit-identical recompute
//    fallback (same token->thread map, f64 order, butterfly, red[] order).
#define B_    64
#define IMG_  1024
#define IND_  64
#define NTHR  256
#define NBLK_IMG (B_ * 4)          // 4 img blocks/batch, 256 rows each
#define NBLK  (NBLK_IMG + B_)      // 320
#define SPIN_MAX 65536

enum {
  W_IN = 0, B_IN = 4, QKV_W = 8, QKV_B = 56, O_W = 68, O_B = 84,
  LN1G = 88, LN1B = 92, FF1W = 96, FF1B = 160, FF2W = 176, FF2B = 240,
  LN2G = 244, LN2B = 248, W_OUT = 252, B_OUT = 256, WTOT = 257
};

struct KArgs {
  const float* in[36];
  unsigned long long* pout;  // [B_][4][3] packed self-validating partials (d_ws)
  float* out;                // [B_][3] (d_out)
};

__device__ __forceinline__ void stage(float* dst, const float* src, int n, int tid) {
  for (int i = tid; i < n; i += NTHR) dst[i] = src[i];
}

__device__ __forceinline__ double wave_sum_d(double v) {
  v += __shfl_xor(v, 1);  v += __shfl_xor(v, 2);  v += __shfl_xor(v, 4);
  v += __shfl_xor(v, 8);  v += __shfl_xor(v, 16); v += __shfl_xor(v, 32);
  return v;
}

// Per-row tail: derived affine constants (uniform, recomputed per thread),
// polynomial softmax sums, LN1 -> FF -> LN2 -> out-projection.
__device__ __forceinline__ float row_tail(const float* __restrict__ w,
                                          float ivr, const float* __restrict__ Mf) {
  float qd[4], qb[4], kd[4], vd[4], vb[4];
#pragma unroll
  for (int j = 0; j < 4; j++) {
    float a0 = 0.f, a1 = 0.f, a2 = 0.f, b0 = 0.f, b2 = 0.f;
#pragma unroll
    for (int e = 0; e < 4; e++) {
      const float we = w[W_IN + e], be = w[B_IN + e];
      a0 += we * w[QKV_W + e * 12 + j];      b0 += be * w[QKV_W + e * 12 + j];
      a1 += we * w[QKV_W + e * 12 + 4 + j];
      a2 += we * w[QKV_W + e * 12 + 8 + j];  b2 += be * w[QKV_W + e * 12 + 8 + j];
    }
    qd[j] = a0; qb[j] = b0 + w[QKV_B + j];
    kd[j] = a1;
    vd[j] = a2; vb[j] = b2 + w[QKV_B + 8 + j];
  }
  float c1 = 0.f, c0 = 0.f;
#pragma unroll
  for (int j = 0; j < 4; j++) { c1 += qd[j] * kd[j]; c0 += qb[j] * kd[j]; }
  float HB[4], HC[4];
#pragma unroll
  for (int j = 0; j < 4; j++) {
    float s1 = 0.f, s2 = 0.f;
#pragma unroll
    for (int f = 0; f < 4; f++) {
      s1 += vd[f] * w[O_W + f * 4 + j];
      s2 += vb[f] * w[O_W + f * 4 + j];
    }
    HB[j] = s1; HC[j] = w[B_IN + j] + s2 + w[O_B + j];
  }

  const float a = 0.5f * (c1 * ivr + c0);      // natural-exp coefficient
  float t = 1.f, S0 = Mf[0], S1 = Mf[1];
#pragma unroll
  for (int k = 1; k <= 12; k++) {
    t *= a * (1.0f / (float)k);
    S0 = fmaf(t, Mf[k], S0);
    S1 = fmaf(t, Mf[k + 1], S1);
  }
  const float rho = S1 / S0;

  float h[4];
#pragma unroll
  for (int j = 0; j < 4; j++) h[j] = w[W_IN + j] * ivr + HB[j] * rho + HC[j];
  {
    const float mn = 0.25f * (h[0] + h[1] + h[2] + h[3]);
    float v = 0.f;
#pragma unroll
    for (int j = 0; j < 4; j++) { const float d = h[j] - mn; v += d * d; }
    const float rs = rsqrtf(v * 0.25f + 1e-5f);
#pragma unroll
    for (int j = 0; j < 4; j++) h[j] = (h[j] - mn) * rs * w[LN1G + j] + w[LN1B + j];
  }
  float f2[4] = {w[FF2B + 0], w[FF2B + 1], w[FF2B + 2], w[FF2B + 3]};
#pragma unroll
  for (int tt = 0; tt < 16; tt++) {
    float u = w[FF1B + tt];
#pragma unroll
    for (int j = 0; j < 4; j++) u += h[j] * w[FF1W + j * 16 + tt];
    u = fmaxf(u, 0.f);
#pragma unroll
    for (int j = 0; j < 4; j++) f2[j] += u * w[FF2W + tt * 4 + j];
  }
  float h2[4];
#pragma unroll
  for (int j = 0; j < 4; j++) h2[j] = h[j] + f2[j];
  {
    const float mn = 0.25f * (h2[0] + h2[1] + h2[2] + h2[3]);
    float v = 0.f;
#pragma unroll
    for (int j = 0; j < 4; j++) { const float d = h2[j] - mn; v += d * d; }
    const float rs = rsqrtf(v * 0.25f + 1e-5f);
#pragma unroll
    for (int j = 0; j < 4; j++) h2[j] = (h2[j] - mn) * rs * w[LN2G + j] + w[LN2B + j];
  }
  float outv = w[B_OUT];
#pragma unroll
  for (int j = 0; j < 4; j++) outv += h2[j] * w[W_OUT + j];
  return outv;
}

__device__ __forceinline__ unsigned long long pack_valid(float v) {
  const unsigned int lo = __float_as_uint(v);
  return (unsigned long long)lo | ((unsigned long long)(~lo) << 32);
}

__global__ __launch_bounds__(NTHR) void fused(KArgs A) {
  const int blk = blockIdx.x;
  const int tid = threadIdx.x;
  const bool is_img = blk < NBLK_IMG;

  __shared__ float w[WTOT];
  __shared__ double mws[4][13];
  __shared__ float red[4][3];
  __shared__ float vals[12];
  __shared__ int okflag;

  int batch, tb;
  const float* xin;
  if (is_img) {
    batch = blk >> 2; xin = A.in[0] + batch * IMG_; tb = 10;
  } else {
    batch = blk - NBLK_IMG; xin = A.in[1] + batch * IND_; tb = 22;
  }

  // ---- stage weights (barrier deferred: moments touch no LDS weights) ----
  stage(w + W_IN,  A.in[is_img ? 2 : 4], 4,  tid);
  stage(w + B_IN,  A.in[is_img ? 3 : 5], 4,  tid);
  stage(w + W_OUT, A.in[is_img ? 6 : 8], 4,  tid);
  stage(w + B_OUT, A.in[is_img ? 7 : 9], 1,  tid);
  stage(w + QKV_W, A.in[tb + 0], 48, tid);
  stage(w + QKV_B, A.in[tb + 1], 12, tid);
  stage(w + O_W,   A.in[tb + 2], 16, tid);
  stage(w + O_B,   A.in[tb + 3], 4,  tid);
  stage(w + LN1G,  A.in[tb + 4], 4,  tid);
  stage(w + LN1B,  A.in[tb + 5], 4,  tid);
  stage(w + FF1W,  A.in[tb + 6], 64, tid);
  stage(w + FF1B,  A.in[tb + 7], 16, tid);
  stage(w + FF2W,  A.in[tb + 8], 64, tid);
  stage(w + FF2B,  A.in[tb + 9], 4,  tid);
  stage(w + LN2G,  A.in[tb + 10], 4, tid);
  stage(w + LN2B,  A.in[tb + 11], 4, tid);

  // ---- tokens straight to registers ----
  float tok[4];
  if (is_img) {
#pragma unroll
    for (int q = 0; q < 4; q++) tok[q] = xin[tid + 256 * q];
  } else {
    tok[0] = (tid < IND_) ? xin[tid] : 0.f;
    tok[1] = tok[2] = tok[3] = 0.f;
  }

  // ---- per-batch moments M_1..M_13 (f64, order identical to winner) ----
  double m[13];
#pragma unroll
  for (int k = 0; k < 13; k++) m[k] = 0.0;
  if (is_img) {
#pragma unroll
    for (int q = 0; q < 4; q++) {            // tokens tid, tid+256, tid+512, tid+768
      const double x = (double)tok[q];
      double px = x;
#pragma unroll
      for (int k = 0; k < 13; k++) { m[k] += px; px *= x; }
    }
  } else {
    const double x = (double)tok[0];         // 0 for tid>=64 -> contributes 0
    double px = x;
#pragma unroll
    for (int k = 0; k < 13; k++) { m[k] += px; px *= x; }
  }
#pragma unroll
  for (int k = 0; k < 13; k++) m[k] = wave_sum_d(m[k]);
  if ((tid & 63) == 0) {
    const int wv = tid >> 6;
#pragma unroll
    for (int k = 0; k < 13; k++) mws[wv][k] = m[k];
  }
  __syncthreads();             // covers weight staging AND mws publication
  float Mf[14];
  Mf[0] = (float)(is_img ? IMG_ : IND_);
#pragma unroll
  for (int k = 0; k < 13; k++)
    Mf[k + 1] = (float)(mws[0][k] + mws[1][k] + mws[2][k] + mws[3][k]);

  // ---- one row per thread: tail + classifier partials ----
  const bool active = is_img || (tid < IND_);
  const int q = blk & 3;
  const float ivr = is_img ? tok[q] : tok[0];
  float p0 = 0.f, p1 = 0.f, p2 = 0.f;
  if (active) {
    const float outv = row_tail(w, ivr, Mf);
    const int g = is_img ? (q * 256 + tid) : (IMG_ + tid);
    const float* wc = A.in[34] + 3 * g;
    p0 = outv * wc[0]; p1 = outv * wc[1]; p2 = outv * wc[2];
  }
#pragma unroll
  for (int msk = 1; msk < 64; msk <<= 1) {
    p0 += __shfl_xor(p0, msk); p1 += __shfl_xor(p1, msk); p2 += __shfl_xor(p2, msk);
  }
  if ((tid & 63) == 0) {
    const int wv = tid >> 6;
    red[wv][0] = p0; red[wv][1] = p1; red[wv][2] = p2;
  }
  __syncthreads();

  if (is_img) {
    // ---- publish self-validating packed partials (relaxed agent atomics) ----
    if (tid == 0) {
      const float s0 = red[0][0] + red[1][0] + red[2][0] + red[3][0];
      const float s1 = red[0][1] + red[1][1] + red[2][1] + red[3][1];
      const float s2 = red[0][2] + red[1][2] + red[2][2] + red[3][2];
      unsigned long long* slot = A.pout + (unsigned long long)(batch * 12 + q * 3);
      __hip_atomic_store(&slot[0], pack_valid(s0), __ATOMIC_RELAXED, __HIP_MEMORY_SCOPE_AGENT);
      __hip_atomic_store(&slot[1], pack_valid(s1), __ATOMIC_RELAXED, __HIP_MEMORY_SCOPE_AGENT);
      __hip_atomic_store(&slot[2], pack_valid(s2), __ATOMIC_RELAXED, __HIP_MEMORY_SCOPE_AGENT);
    }
    return;
  }

  // ---- ind block = per-batch finalizer ----
  // own ind partial (every thread computes the same sums from red)
  const float si0 = red[0][0] + red[1][0] + red[2][0] + red[3][0];
  const float si1 = red[0][1] + red[1][1] + red[2][1] + red[3][1];
  const float si2 = red[0][2] + red[1][2] + red[2][2] + red[3][2];

  // bounded poll of the 4x3 img slots (12 lanes of wave 0)
  bool got = false;
  if (tid < 12) {
    unsigned long long* slot = A.pout + (unsigned long long)(batch * 12 + tid);
    for (int it = 0; it < SPIN_MAX; ++it) {
      const unsigned long long v =
          __hip_atomic_load(slot, __ATOMIC_RELAXED, __HIP_MEMORY_SCOPE_AGENT);
      if ((unsigned int)(v >> 32) == ~(unsigned int)v) {    // poison has hi==lo
        vals[tid] = __uint_as_float((unsigned int)v);
        got = true;
        break;
      }
      __builtin_amdgcn_s_sleep(1);
    }
  }
  const unsigned long long bal = __ballot(got);
  if (tid == 0) okflag = ((bal & 0xFFFull) == 0xFFFull);
  __syncthreads();

  float sq[4][3];                 // fallback img partials (bit-identical path)
  const bool fb = !okflag;
  if (fb) {
    // re-stage t1 weights (everyone is done reading the t2 set)
    stage(w + W_IN,  A.in[2], 4,  tid);
    stage(w + B_IN,  A.in[3], 4,  tid);
    stage(w + W_OUT, A.in[6], 4,  tid);
    stage(w + B_OUT, A.in[7], 1,  tid);
    stage(w + QKV_W, A.in[10], 48, tid);
    stage(w + QKV_B, A.in[11], 12, tid);
    stage(w + O_W,   A.in[12], 16, tid);
    stage(w + O_B,   A.in[13], 4,  tid);
    stage(w + LN1G,  A.in[14], 4,  tid);
    stage(w + LN1B,  A.in[15], 4,  tid);
    stage(w + FF1W,  A.in[16], 64, tid);
    stage(w + FF1B,  A.in[17], 16, tid);
    stage(w + FF2W,  A.in[18], 64, tid);
    stage(w + FF2B,  A.in[19], 4,  tid);
    stage(w + LN2G,  A.in[20], 4, tid);
    stage(w + LN2B,  A.in[21], 4, tid);

    const float* xinI = A.in[0] + batch * IMG_;
    float tokI[4];
#pragma unroll
    for (int qq = 0; qq < 4; qq++) tokI[qq] = xinI[tid + 256 * qq];

    double mI[13];
#pragma unroll
    for (int k = 0; k < 13; k++) mI[k] = 0.0;
#pragma unroll
    for (int qq = 0; qq < 4; qq++) {
      const double x = (double)tokI[qq];
      double px = x;
#pragma unroll
      for (int k = 0; k < 13; k++) { mI[k] += px; px *= x; }
    }
#pragma unroll
    for (int k = 0; k < 13; k++) mI[k] = wave_sum_d(mI[k]);
    if ((tid & 63) == 0) {
      const int wv = tid >> 6;
#pragma unroll
      for (int k = 0; k < 13; k++) mws[wv][k] = mI[k];
    }
    __syncthreads();             // covers w restage AND mws
    float MfI[14];
    MfI[0] = (float)IMG_;
#pragma unroll
    for (int k = 0; k < 13; k++)
      MfI[k + 1] = (float)(mws[0][k] + mws[1][k] + mws[2][k] + mws[3][k]);

    for (int qq = 0; qq < 4; qq++) {
      const float outv = row_tail(w, tokI[qq], MfI);
      const float* wc = A.in[34] + 3 * (qq * 256 + tid);
      float a0 = outv * wc[0], a1 = outv * wc[1], a2 = outv * wc[2];
#pragma unroll
      for (int msk = 1; msk < 64; msk <<= 1) {
        a0 += __shfl_xor(a0, msk); a1 += __shfl_xor(a1, msk); a2 += __shfl_xor(a2, msk);
      }
      if ((tid & 63) == 0) {
        const int wv = tid >> 6;
        red[wv][0] = a0; red[wv][1] = a1; red[wv][2] = a2;
      }
      __syncthreads();
#pragma unroll
      for (int c = 0; c < 3; c++)
        sq[qq][c] = red[0][c] + red[1][c] + red[2][c] + red[3][c];
      __syncthreads();           // before next qq overwrites red
    }
  }

  if (tid == 0) {
    const float* bc = A.in[35];
    float z[3];
#pragma unroll
    for (int c = 0; c < 3; c++) {
      float s = bc[c];
      if (fb) {
#pragma unroll
        for (int i = 0; i < 4; i++) s += sq[i][c];            // winner order
      } else {
#pragma unroll
        for (int i = 0; i < 4; i++) s += vals[i * 3 + c];     // winner order
      }
      s += (c == 0) ? si0 : (c == 1) ? si1 : si2;             // own ind partial
      z[c] = s;
    }
    const float mx = fmaxf(z[0], fmaxf(z[1], z[2]));
    const float e0 = __expf(z[0] - mx), e1 = __expf(z[1] - mx), e2 = __expf(z[2] - mx);
    const float rs = 1.f / (e0 + e1 + e2);
    A.out[batch * 3 + 0] = e0 * rs;
    A.out[batch * 3 + 1] = e1 * rs;
    A.out[batch * 3 + 2] = e2 * rs;
  }
}

extern "C" void kernel_launch(void* const* d_in, const int* in_sizes, int n_in,
                              void* d_out, int out_size, void* d_ws, size_t ws_size,
                              hipStream_t stream) {
  KArgs A;
  for (int i = 0; i < 36; i++) A.in[i] = (const float*)d_in[i];
  A.pout = (unsigned long long*)d_ws;   // 768 u64 slots, self-validating
  A.out  = (float*)d_out;

  fused<<<NBLK, NTHR, 0, stream>>>(A);
}